// Round 1
// baseline (581.763 us; speedup 1.0000x reference)
//
#include <hip/hip_runtime.h>
#include <hip/hip_fp16.h>
#include <cstdint>
#include <cstddef>

#define BN_EPS 1e-5f
#define FPSCALE 268435456.0f  // 2^28
#define PPS 8                 // packed pad stride (u64s): one 64B line per node

typedef _Float16 half8 __attribute__((ext_vector_type(8)));
typedef float floatx4 __attribute__((ext_vector_type(4)));

// ---------------------------------------------------------------------------
// fp16 helpers
// ---------------------------------------------------------------------------
__device__ __forceinline__ float loadS(const __half* p) { return __half2float(*p); }
__device__ __forceinline__ float2 load2(const __half* p) {
    return __half22float2(*(const __half2*)p);
}
__device__ __forceinline__ void storeS(float* p, float v) { *p = v; }
__device__ __forceinline__ void storeS(__half* p, float v) { *p = __float2half(v); }
__device__ __forceinline__ void store2(float* p, float a, float b) {
    *(float2*)p = make_float2(a, b);
}
__device__ __forceinline__ void store2(__half* p, float a, float b) {
    *(__half2*)p = __floats2half2_rn(a, b);
}
// packed edge: (src << 15) | (fp16 bits of wn, sign stripped); 0 => src=0, wn=0
__device__ __forceinline__ float wn_of(unsigned v) {
    __half_raw hr; hr.x = (unsigned short)(v & 0x7fffu);
    return __half2float((__half)hr);
}

static __device__ __forceinline__ int load_edge(const void* ei, int mode64, long long pos) {
    if (mode64) return (int)((const long long*)ei)[pos];
    return ((const int*)ei)[pos];
}

// ---------------------------------------------------------------------------
// init: [0,nb) fill packed=0 (padded slots) | block nb: detect int64-vs-int32
// | rest: W->WT fp16
// ---------------------------------------------------------------------------
__global__ __launch_bounds__(256) void init_kernel(const unsigned* __restrict__ eiw, int nwords,
                                                   int* __restrict__ mode,
                                                   unsigned long long* __restrict__ packed, int N,
                                                   const float* __restrict__ W1,
                                                   const float* __restrict__ W2,
                                                   const float* __restrict__ W3,
                                                   _Float16* __restrict__ WT1,
                                                   _Float16* __restrict__ WT2,
                                                   _Float16* __restrict__ WT3, int nb) {
    __shared__ unsigned red[256];
    const int bid = (int)blockIdx.x;
    const int tid = (int)threadIdx.x;
    if (bid < nb) {
        int i = bid * 256 + tid;
        if (i < N) packed[(size_t)i * PPS] = 0ULL;
        return;
    }
    if (bid == nb) {
        unsigned m = 0;
        for (int i = 1 + 2 * tid; i < nwords; i += 512) m |= eiw[i];
        red[tid] = m;
        __syncthreads();
        for (int s = 128; s > 0; s >>= 1) {
            if (tid < s) red[tid] |= red[tid + s];
            __syncthreads();
        }
        if (tid == 0) mode[0] = (red[0] == 0) ? 1 : 0;
        return;
    }
    const int t_ = bid - nb - 1;  // 0..159
    if (t_ < 64) {
        int t = t_ * 256 + tid;            // 128x128
        int n = t / 128, k = t % 128;
        WT1[t] = (_Float16)W1[k * 128 + n];
    } else if (t_ < 128) {
        int t = (t_ - 64) * 256 + tid;
        int n = t / 128, k = t % 128;
        WT2[t] = (_Float16)W2[k * 128 + n];
    } else {
        int t = (t_ - 128) * 256 + tid;    // 128x64
        int n = t / 128, k = t % 128;
        WT3[t] = (_Float16)W3[k * 64 + n];
    }
}

// ---------------------------------------------------------------------------
// MFMA GEMM body WITH LDS staging (used by standalone gemm kernels L2/L3).
// v_mfma_f32_16x16x32_f16, 4 waves, 64 rows/block.
// ---------------------------------------------------------------------------
template <int M, bool BN, typename TI>
__device__ __forceinline__ void gemm_body(int gbid, const TI* __restrict__ X,
                                          const _Float16* __restrict__ WTg,
                                          const float* __restrict__ sc,
                                          const float* __restrict__ sh,
                                          __half* __restrict__ Hout, int N,
                                          _Float16* WT /* LDS, M*136 */) {
    constexpr int CT = M / 16;
    constexpr int LDK = 136;

    for (int t = threadIdx.x; t < M * 16; t += 256) {
        int n = t / 16, seg = t % 16;
        *(half8*)&WT[n * LDK + seg * 8] = *(const half8*)&WTg[n * 128 + seg * 8];
    }
    __syncthreads();

    const int wave = (int)threadIdx.x >> 6;
    const int lane = (int)threadIdx.x & 63;
    const int qd = lane >> 4;
    const int ln = lane & 15;
    const int tile0 = gbid * 64 + wave * 16;
    int ar = tile0 + ln;
    if (ar >= N) ar = N - 1;  // clamp (stores guarded)

    half8 aF[4];
    const TI* xr = X + (size_t)ar * 128 + qd * 8;
#pragma unroll
    for (int kb = 0; kb < 4; ++kb) {
        float vv[8];
        if constexpr (sizeof(TI) == 4) {
            float4 v0 = *(const float4*)(xr + kb * 32);
            float4 v1 = *(const float4*)(xr + kb * 32 + 4);
            vv[0] = v0.x; vv[1] = v0.y; vv[2] = v0.z; vv[3] = v0.w;
            vv[4] = v1.x; vv[5] = v1.y; vv[6] = v1.z; vv[7] = v1.w;
        } else {
            half8 raw = *(const half8*)(xr + kb * 32);
#pragma unroll
            for (int j = 0; j < 8; ++j) vv[j] = (float)raw[j];
        }
        if (BN) {
            const int kbase = kb * 32 + qd * 8;
#pragma unroll
            for (int j = 0; j < 8; ++j)
                vv[j] = fmaxf(fmaf(vv[j], sc[kbase + j], sh[kbase + j]), 0.0f);
        }
        half8 a;
#pragma unroll
        for (int j = 0; j < 8; ++j) a[j] = (_Float16)vv[j];
        aF[kb] = a;
    }

#pragma unroll
    for (int ct = 0; ct < CT; ++ct) {
        floatx4 acc = {0.0f, 0.0f, 0.0f, 0.0f};
#pragma unroll
        for (int kb = 0; kb < 4; ++kb) {
            half8 b = *(const half8*)&WT[(ct * 16 + ln) * LDK + kb * 32 + qd * 8];
            acc = __builtin_amdgcn_mfma_f32_16x16x32_f16(aF[kb], b, acc, 0, 0, 0);
        }
#pragma unroll
        for (int r = 0; r < 4; ++r) {
            int orow = tile0 + qd * 4 + r;
            if (orow < N) Hout[(size_t)orow * M + ct * 16 + ln] = __float2half(acc[r]);
        }
    }
}

// ---------------------------------------------------------------------------
// GEMM1 body WITHOUT LDS: B fragments read directly from global WT1g (32 KB,
// L1-resident per CU after first touch). Zero LDS -> hist blocks in the fused
// kernel get full occupancy (8 blocks/CU at VGPR<=64).
// ---------------------------------------------------------------------------
__device__ __forceinline__ void gemm1_nolds(int gbid, const float* __restrict__ X,
                                            const _Float16* __restrict__ WTg,
                                            __half* __restrict__ Hout, int N) {
    const int wave = (int)threadIdx.x >> 6;
    const int lane = (int)threadIdx.x & 63;
    const int qd = lane >> 4;
    const int ln = lane & 15;
    const int tile0 = gbid * 64 + wave * 16;
    int ar = tile0 + ln;
    if (ar >= N) ar = N - 1;  // clamp (stores guarded)

    half8 aF[4];
    const float* xr = X + (size_t)ar * 128 + qd * 8;
#pragma unroll
    for (int kb = 0; kb < 4; ++kb) {
        float4 v0 = *(const float4*)(xr + kb * 32);
        float4 v1 = *(const float4*)(xr + kb * 32 + 4);
        half8 a;
        a[0] = (_Float16)v0.x; a[1] = (_Float16)v0.y;
        a[2] = (_Float16)v0.z; a[3] = (_Float16)v0.w;
        a[4] = (_Float16)v1.x; a[5] = (_Float16)v1.y;
        a[6] = (_Float16)v1.z; a[7] = (_Float16)v1.w;
        aF[kb] = a;
    }

#pragma unroll 1
    for (int ct = 0; ct < 8; ++ct) {
        floatx4 acc = {0.0f, 0.0f, 0.0f, 0.0f};
#pragma unroll
        for (int kb = 0; kb < 4; ++kb) {
            half8 b = *(const half8*)&WTg[(size_t)(ct * 16 + ln) * 128 + kb * 32 + qd * 8];
            acc = __builtin_amdgcn_mfma_f32_16x16x32_f16(aF[kb], b, acc, 0, 0, 0);
        }
#pragma unroll
        for (int r = 0; r < 4; ++r) {
            int orow = tile0 + qd * 4 + r;
            if (orow < N) Hout[(size_t)orow * 128 + ct * 16 + ln] = __float2half(acc[r]);
        }
    }
}

// ---------------------------------------------------------------------------
// Fused: [0,HB) = degree histogram (4 edges/thread, 4 atomics in flight,
// padded one-line-per-node packed[]) ; [HB,..) = GEMM1 (no LDS).
// ---------------------------------------------------------------------------
__global__ __launch_bounds__(256, 8) void hist_gemm1_kernel(const void* __restrict__ ei,
                                                            const float* __restrict__ ew,
                                                            unsigned long long* __restrict__ packed,
                                                            unsigned* __restrict__ rank,
                                                            const int* __restrict__ mode, int E, int HB,
                                                            const float* __restrict__ X,
                                                            const _Float16* __restrict__ WT1g,
                                                            __half* __restrict__ Hout, int N) {
    if ((int)blockIdx.x >= HB) {
        gemm1_nolds((int)blockIdx.x - HB, X, WT1g, Hout, N);
        return;
    }
    const int md = *mode;
    const int e = (int)blockIdx.x * 1024 + (int)threadIdx.x * 4;
    if (e + 3 < E) {
        long long d0, d1, d2, d3;
        if (md) {
            const long long* p = (const long long*)ei + (long long)E + e;
            longlong2 a = *(const longlong2*)p;
            longlong2 b = *(const longlong2*)(p + 2);
            d0 = a.x; d1 = a.y; d2 = b.x; d3 = b.y;
        } else {
            const int* p = (const int*)ei + (long long)E + e;
            int4 a = *(const int4*)p;
            d0 = a.x; d1 = a.y; d2 = a.z; d3 = a.w;
        }
        float4 w4 = *(const float4*)(ew + e);
        unsigned long long o0 = atomicAdd(&packed[(size_t)d0 * PPS],
                                          (1ULL << 40) | (unsigned long long)(w4.x * FPSCALE));
        unsigned long long o1 = atomicAdd(&packed[(size_t)d1 * PPS],
                                          (1ULL << 40) | (unsigned long long)(w4.y * FPSCALE));
        unsigned long long o2 = atomicAdd(&packed[(size_t)d2 * PPS],
                                          (1ULL << 40) | (unsigned long long)(w4.z * FPSCALE));
        unsigned long long o3 = atomicAdd(&packed[(size_t)d3 * PPS],
                                          (1ULL << 40) | (unsigned long long)(w4.w * FPSCALE));
        uint4 r4;
        r4.x = (unsigned)(o0 >> 40); r4.y = (unsigned)(o1 >> 40);
        r4.z = (unsigned)(o2 >> 40); r4.w = (unsigned)(o3 >> 40);
        *(uint4*)(rank + e) = r4;
    } else {
#pragma unroll 1
        for (int k = 0; k < 4; ++k) {
            int ee = e + k;
            if (ee >= E) break;
            int d = load_edge(ei, md, (long long)E + ee);
            unsigned long long contrib =
                (1ULL << 40) | (unsigned long long)(ew[ee] * FPSCALE);
            unsigned long long old = atomicAdd(&packed[(size_t)d * PPS], contrib);
            rank[ee] = (unsigned)(old >> 40);
        }
    }
}

// ---------------------------------------------------------------------------
// unpack (cnt, dinv) + per-2048-chunk sum (scanA) in one pass
// ---------------------------------------------------------------------------
__global__ __launch_bounds__(256) void unpack_scanA_kernel(const unsigned long long* __restrict__ packed,
                                                           float* __restrict__ dinv,
                                                           int* __restrict__ cnt,
                                                           int* __restrict__ bsum, int N) {
    __shared__ int red[256];
    const int tid = (int)threadIdx.x;
    const int base = (int)blockIdx.x * 2048 + tid * 8;
    int s = 0;
#pragma unroll
    for (int j = 0; j < 8; ++j) {
        int idx = base + j;
        if (idx < N) {
            unsigned long long p = packed[(size_t)idx * PPS];
            int c = (int)(p >> 40);
            cnt[idx] = c;
            dinv[idx] = rsqrtf(1.0f + (float)(p & 0xFFFFFFFFFFULL) * (1.0f / FPSCALE));
            s += c;
        }
    }
    red[tid] = s;
    __syncthreads();
    for (int st = 128; st > 0; st >>= 1) {
        if (tid < st) red[tid] += red[tid + st];
        __syncthreads();
    }
    if (tid == 0) bsum[blockIdx.x] = red[0];
}

// row_start: local exclusive scan + direct sum over bsum[0..bid) (G<=64, cheap)
__global__ __launch_bounds__(256) void scanC_kernel(const int* __restrict__ cnt,
                                                    const int* __restrict__ bsum,
                                                    int* __restrict__ row_start, int N) {
    __shared__ int lds[256];
    const int tid = (int)threadIdx.x;
    int gbase = 0;
    for (int j = 0; j < (int)blockIdx.x; ++j) gbase += bsum[j];
    const int base = (int)blockIdx.x * 2048 + tid * 8;
    int vals[8];
    int s = 0;
#pragma unroll
    for (int j = 0; j < 8; ++j) {
        int idx = base + j;
        int v = (idx < N) ? cnt[idx] : 0;
        vals[j] = s;
        s += v;
    }
    lds[tid] = s;
    __syncthreads();
    for (int off = 1; off < 256; off <<= 1) {
        int t = 0;
        if (tid >= off) t = lds[tid - off];
        __syncthreads();
        lds[tid] += t;
        __syncthreads();
    }
    int excl = lds[tid] - s;
    int b = gbase + excl;
#pragma unroll
    for (int j = 0; j < 8; ++j) {
        int idx = base + j;
        if (idx < N) row_start[idx] = b + vals[j];
    }
}

// ---------------------------------------------------------------------------
// Atomic-free scatter (slot = row_start[d] + rank[e], 4B payload) + last block
// zeroes the BN stats accumulators for layer 1.
// ---------------------------------------------------------------------------
__global__ __launch_bounds__(256) void scatter_zero_kernel(const void* __restrict__ ei,
                                                           const float* __restrict__ ew,
                                                           const float* __restrict__ dinv,
                                                           const int* __restrict__ row_start,
                                                           const unsigned* __restrict__ rank,
                                                           unsigned* __restrict__ edata,
                                                           const int* __restrict__ mode, int E, int EBK,
                                                           float* __restrict__ gsum,
                                                           float* __restrict__ gsq) {
    if ((int)blockIdx.x == EBK) {
        if (threadIdx.x < 128) { gsum[threadIdx.x] = 0.0f; gsq[threadIdx.x] = 0.0f; }
        return;
    }
    int e = (int)blockIdx.x * 256 + (int)threadIdx.x;
    if (e >= E) return;
    int md = *mode;
    int s = load_edge(ei, md, e);
    int d = load_edge(ei, md, (long long)E + e);
    float wn = dinv[s] * ew[e] * dinv[d];
    unsigned hb = (unsigned)__half_as_ushort(__float2half(wn)) & 0x7fffu;
    edata[row_start[d] + (int)rank[e]] = ((unsigned)s << 15) | hb;
}

// ---------------------------------------------------------------------------
// CSR aggregation v2: one WAVE per node (4 nodes / 256-thr block). No LDS, no
// barriers: each lane holds one edge word, broadcast via __shfl; 8-deep
// unrolled gathers; zero-padded tail (pad word 0 -> src 0, wn 0).
// ---------------------------------------------------------------------------
template <int D, bool BIAS, typename TY>
__global__ __launch_bounds__(256) void agg_kernel(const __half* __restrict__ H,
                                                  const unsigned* __restrict__ edata,
                                                  const int* __restrict__ row_start,
                                                  const int* __restrict__ cnt,
                                                  const float* __restrict__ dinv,
                                                  const float* __restrict__ bias,
                                                  TY* __restrict__ Y, int N) {
    constexpr int VPT = D / 64;  // 2 (D=128) or 1 (D=64)
    const int lane = (int)threadIdx.x & 63;
    const int i = (int)blockIdx.x * 4 + ((int)threadIdx.x >> 6);
    if (i >= N) return;
    const int c0 = lane * VPT;
    const float di = dinv[i];
    const float dii = di * di;

    float acc0, acc1 = 0.0f;
    if constexpr (VPT == 2) {
        float2 h = load2(H + (size_t)i * D + c0);
        acc0 = dii * h.x;
        acc1 = dii * h.y;
    } else {
        acc0 = dii * loadS(H + (size_t)i * D + c0);
    }

    const int base = row_start[i];
    const int n = cnt[i];
    for (int off = 0; off < n; off += 64) {
        const int rem = n - off;
        unsigned ev = 0;
        if (lane < rem) ev = edata[base + off + lane];
        const int mm = min(64, rem);
        for (int j = 0; j < mm; j += 8) {
            const unsigned e0 = __shfl(ev, j),     e1 = __shfl(ev, j + 1);
            const unsigned e2 = __shfl(ev, j + 2), e3 = __shfl(ev, j + 3);
            const unsigned e4 = __shfl(ev, j + 4), e5 = __shfl(ev, j + 5);
            const unsigned e6 = __shfl(ev, j + 6), e7 = __shfl(ev, j + 7);
            if constexpr (VPT == 2) {
                float2 h0 = load2(H + (size_t)(e0 >> 15) * D + c0);
                float2 h1 = load2(H + (size_t)(e1 >> 15) * D + c0);
                float2 h2 = load2(H + (size_t)(e2 >> 15) * D + c0);
                float2 h3 = load2(H + (size_t)(e3 >> 15) * D + c0);
                float2 h4 = load2(H + (size_t)(e4 >> 15) * D + c0);
                float2 h5 = load2(H + (size_t)(e5 >> 15) * D + c0);
                float2 h6 = load2(H + (size_t)(e6 >> 15) * D + c0);
                float2 h7 = load2(H + (size_t)(e7 >> 15) * D + c0);
                acc0 = fmaf(wn_of(e0), h0.x, acc0); acc1 = fmaf(wn_of(e0), h0.y, acc1);
                acc0 = fmaf(wn_of(e1), h1.x, acc0); acc1 = fmaf(wn_of(e1), h1.y, acc1);
                acc0 = fmaf(wn_of(e2), h2.x, acc0); acc1 = fmaf(wn_of(e2), h2.y, acc1);
                acc0 = fmaf(wn_of(e3), h3.x, acc0); acc1 = fmaf(wn_of(e3), h3.y, acc1);
                acc0 = fmaf(wn_of(e4), h4.x, acc0); acc1 = fmaf(wn_of(e4), h4.y, acc1);
                acc0 = fmaf(wn_of(e5), h5.x, acc0); acc1 = fmaf(wn_of(e5), h5.y, acc1);
                acc0 = fmaf(wn_of(e6), h6.x, acc0); acc1 = fmaf(wn_of(e6), h6.y, acc1);
                acc0 = fmaf(wn_of(e7), h7.x, acc0); acc1 = fmaf(wn_of(e7), h7.y, acc1);
            } else {
                float h0 = loadS(H + (size_t)(e0 >> 15) * D + c0);
                float h1 = loadS(H + (size_t)(e1 >> 15) * D + c0);
                float h2 = loadS(H + (size_t)(e2 >> 15) * D + c0);
                float h3 = loadS(H + (size_t)(e3 >> 15) * D + c0);
                float h4 = loadS(H + (size_t)(e4 >> 15) * D + c0);
                float h5 = loadS(H + (size_t)(e5 >> 15) * D + c0);
                float h6 = loadS(H + (size_t)(e6 >> 15) * D + c0);
                float h7 = loadS(H + (size_t)(e7 >> 15) * D + c0);
                acc0 = fmaf(wn_of(e0), h0, acc0);
                acc0 = fmaf(wn_of(e1), h1, acc0);
                acc0 = fmaf(wn_of(e2), h2, acc0);
                acc0 = fmaf(wn_of(e3), h3, acc0);
                acc0 = fmaf(wn_of(e4), h4, acc0);
                acc0 = fmaf(wn_of(e5), h5, acc0);
                acc0 = fmaf(wn_of(e6), h6, acc0);
                acc0 = fmaf(wn_of(e7), h7, acc0);
            }
        }
    }

    if constexpr (VPT == 2) {
        if (BIAS) { acc0 += bias[c0]; acc1 += bias[c0 + 1]; }
        store2(Y + (size_t)i * D + c0, acc0, acc1);
    } else {
        if (BIAS) acc0 += bias[c0];
        storeS(Y + (size_t)i * D + c0, acc0);
    }
}

// ---------------------------------------------------------------------------
// GEMM dispatch wrapper; optional extra block zeroes next layer's BN stats.
// ---------------------------------------------------------------------------
template <int M, bool BN, typename TI, bool ZERO>
__global__ __launch_bounds__(256) void gemm_mfma_kernel(const TI* __restrict__ X,
                                                        const _Float16* __restrict__ WTg,
                                                        const float* __restrict__ sc,
                                                        const float* __restrict__ sh,
                                                        __half* __restrict__ Hout, int N,
                                                        float* __restrict__ gsum,
                                                        float* __restrict__ gsq, int GB) {
    __shared__ _Float16 WT[M * 136];
    if (ZERO && (int)blockIdx.x == GB) {
        if (threadIdx.x < 128) { gsum[threadIdx.x] = 0.0f; gsq[threadIdx.x] = 0.0f; }
        return;
    }
    gemm_body<M, BN, TI>(blockIdx.x, X, WTg, sc, sh, Hout, N, WT);
}

// ---------------------------------------------------------------------------
// BatchNorm statistics (fp16 Y)
// ---------------------------------------------------------------------------
__global__ void stats_kernel(const __half* __restrict__ Y, float* __restrict__ gsum,
                             float* __restrict__ gsq, int N) {
    __shared__ float ls[256], lq[256];
    const int tid = threadIdx.x;
    const int c = tid & 127;
    const int half_ = tid >> 7;
    float s = 0.0f, q = 0.0f;
    for (int row = blockIdx.x * 2 + half_; row < N; row += 512) {
        float v = __half2float(Y[(size_t)row * 128 + c]);
        s += v;
        q = fmaf(v, v, q);
    }
    ls[tid] = s; lq[tid] = q;
    __syncthreads();
    if (tid < 128) {
        atomicAdd(&gsum[c], ls[tid] + ls[tid + 128]);
        atomicAdd(&gsq[c],  lq[tid] + lq[tid + 128]);
    }
}

__global__ void finalize_stats_kernel(const float* __restrict__ gsum, const float* __restrict__ gsq,
                                      const float* __restrict__ gamma, const float* __restrict__ beta,
                                      float* __restrict__ sc, float* __restrict__ sh, int N) {
    int t = threadIdx.x;
    if (t < 128) {
        float inv_n = 1.0f / (float)N;
        float mean = gsum[t] * inv_n;
        float var = gsq[t] * inv_n - mean * mean;
        float scale = gamma[t] * rsqrtf(var + BN_EPS);
        sc[t] = scale;
        sh[t] = beta[t] - mean * scale;
    }
}

// ---------------------------------------------------------------------------
// Launch
// ---------------------------------------------------------------------------
extern "C" void kernel_launch(void* const* d_in, const int* in_sizes, int n_in,
                              void* d_out, int out_size, void* d_ws, size_t ws_size,
                              hipStream_t stream) {
    const float* x   = (const float*)d_in[0];
    const void*  ei  = d_in[1];
    const float* ew  = (const float*)d_in[2];
    const float* W1  = (const float*)d_in[3];
    const float* W2  = (const float*)d_in[5];
    const float* W3  = (const float*)d_in[7];
    const float* b3  = (const float*)d_in[8];
    const float* g1  = (const float*)d_in[9];
    const float* be1 = (const float*)d_in[10];
    const float* g2  = (const float*)d_in[11];
    const float* be2 = (const float*)d_in[12];
    float* out = (float*)d_out;

    const int N = in_sizes[0] / 128;   // 100000 (edge packing needs N <= 2^17)
    const int E = in_sizes[2];
    const int G = (N + 2047) / 2048;

    char* w = (char*)d_ws;
    size_t off = 0;
    auto alloc = [&](size_t bytes) -> void* {
        void* p = w + off;
        off += (bytes + 255) & ~(size_t)255;
        return p;
    };
    unsigned long long* packed = (unsigned long long*)alloc((size_t)N * 8 * PPS);
    float* dinv      = (float*)alloc((size_t)N * 4);
    int*   cnt       = (int*)  alloc((size_t)N * 4);
    int*   row_start = (int*)  alloc((size_t)N * 4);
    unsigned* rank   = (unsigned*)alloc((size_t)E * 4);
    unsigned* edata  = (unsigned*)alloc((size_t)E * 4);
    int*   bsum      = (int*)  alloc((size_t)G * 4);
    int*   mode      = (int*)  alloc(256);
    float* gsum      = (float*)alloc(128 * 4);
    float* gsq       = (float*)alloc(128 * 4);
    float* scb       = (float*)alloc(128 * 4);
    float* shb       = (float*)alloc(128 * 4);
    _Float16* WT1    = (_Float16*)alloc(128 * 128 * 2);
    _Float16* WT2    = (_Float16*)alloc(128 * 128 * 2);
    _Float16* WT3    = (_Float16*)alloc(128 * 64 * 2);
    __half* H        = (__half*)alloc((size_t)N * 128 * 2);  // gemm out / agg in
    __half* Yh       = (__half*)alloc((size_t)N * 128 * 2);  // agg out / next gemm in
    (void)ws_size; (void)n_in; (void)out_size;

    const int nb  = (N + 255) / 256;
    const int ebk = (E + 255) / 256;
    const int ehb = (E + 1023) / 1024;   // hist blocks: 4 edges/thread
    const int gb  = (N + 63) / 64;
    const int ab  = (N + 3) / 4;

    // 1: fill packed + detect dtype + W transposes (all independent)
    init_kernel<<<nb + 1 + 160, 256, 0, stream>>>((const unsigned*)ei, 4096, mode, packed, N,
                                                  W1, W2, W3, WT1, WT2, WT3, nb);
    // 2: histogram (atomic-latency-bound, first) fused with GEMM1 (no LDS) — overlap
    hist_gemm1_kernel<<<ehb + gb, 256, 0, stream>>>(ei, ew, packed, rank, mode, E, ehb,
                                                    x, WT1, H, N);
    // 3-4: unpack + scan -> row_start
    unpack_scanA_kernel<<<G, 256, 0, stream>>>(packed, dinv, cnt, bsum, N);
    scanC_kernel<<<G, 256, 0, stream>>>(cnt, bsum, row_start, N);
    // 5: atomic-free scatter (+ zero BN stats for L1)
    scatter_zero_kernel<<<ebk + 1, 256, 0, stream>>>(ei, ew, dinv, row_start, rank, edata,
                                                     mode, E, ebk, gsum, gsq);

    // ---- L1: Yh = Ahat*H ----
    agg_kernel<128, false, __half><<<ab, 256, 0, stream>>>(H, edata, row_start, cnt, dinv, nullptr, Yh, N);
    stats_kernel<<<256, 256, 0, stream>>>(Yh, gsum, gsq, N);
    finalize_stats_kernel<<<1, 128, 0, stream>>>(gsum, gsq, g1, be1, scb, shb, N);

    // ---- L2: H = relu(bn(Yh))@W2 ; Yh = Ahat*H ----
    gemm_mfma_kernel<128, true, __half, true><<<gb + 1, 256, 0, stream>>>(Yh, WT2, scb, shb, H, N, gsum, gsq, gb);
    agg_kernel<128, false, __half><<<ab, 256, 0, stream>>>(H, edata, row_start, cnt, dinv, nullptr, Yh, N);
    stats_kernel<<<256, 256, 0, stream>>>(Yh, gsum, gsq, N);
    finalize_stats_kernel<<<1, 128, 0, stream>>>(gsum, gsq, g2, be2, scb, shb, N);

    // ---- L3: H64 = relu(bn(Yh))@W3 ; out = Ahat*H64 + b3 ----
    gemm_mfma_kernel<64, true, __half, false><<<gb, 256, 0, stream>>>(Yh, WT3, scb, shb, H, N, nullptr, nullptr, gb);
    agg_kernel<64, true, float><<<ab, 256, 0, stream>>>(H, edata, row_start, cnt, dinv, b3, out, N);
}

// Round 3
// 573.235 us; speedup vs baseline: 1.0149x; 1.0149x over previous
//
#include <hip/hip_runtime.h>
#include <hip/hip_fp16.h>
#include <cstdint>
#include <cstddef>

#define BN_EPS 1e-5f
#define FPSCALE 268435456.0f  // 2^28
#define NCOPY 8               // one histogram copy per XCD

typedef _Float16 half8 __attribute__((ext_vector_type(8)));
typedef float floatx4 __attribute__((ext_vector_type(4)));

// ---------------------------------------------------------------------------
// fp16 helpers
// ---------------------------------------------------------------------------
__device__ __forceinline__ float loadS(const __half* p) { return __half2float(*p); }
__device__ __forceinline__ float2 load2(const __half* p) {
    return __half22float2(*(const __half2*)p);
}
__device__ __forceinline__ void storeS(float* p, float v) { *p = v; }
__device__ __forceinline__ void storeS(__half* p, float v) { *p = __float2half(v); }
__device__ __forceinline__ void store2(float* p, float a, float b) {
    *(float2*)p = make_float2(a, b);
}
__device__ __forceinline__ void store2(__half* p, float a, float b) {
    *(__half2*)p = __floats2half2_rn(a, b);
}
// packed edge: (src << 15) | (fp16 bits of wn, sign stripped); 0 => src=0, wn=0
__device__ __forceinline__ float wn_of(unsigned v) {
    __half_raw hr; hr.x = (unsigned short)(v & 0x7fffu);
    return __half2float((__half)hr);
}

static __device__ __forceinline__ int load_edge(const void* ei, int mode64, long long pos) {
    if (mode64) return (int)((const long long*)ei)[pos];
    return ((const int*)ei)[pos];
}

// physical XCD id (0..7) — verified available on gfx950 (HW_REG_XCC_ID,
// learn_hip m09). Masked so a bad read can never index out of bounds.
__device__ __forceinline__ unsigned xcc_id() {
    unsigned v;
    asm volatile("s_getreg_b32 %0, hwreg(HW_REG_XCC_ID)" : "=s"(v));
    return v & 7u;
}

// ---------------------------------------------------------------------------
// init: [0,nb) zero all NCOPY histogram copies | block nb: detect int64-vs-
// int32 | rest: W->WT fp16
// ---------------------------------------------------------------------------
__global__ __launch_bounds__(256) void init_kernel(const unsigned* __restrict__ eiw, int nwords,
                                                   int* __restrict__ mode,
                                                   unsigned long long* __restrict__ packed, int N,
                                                   const float* __restrict__ W1,
                                                   const float* __restrict__ W2,
                                                   const float* __restrict__ W3,
                                                   _Float16* __restrict__ WT1,
                                                   _Float16* __restrict__ WT2,
                                                   _Float16* __restrict__ WT3, int nb) {
    __shared__ unsigned red[256];
    const int bid = (int)blockIdx.x;
    const int tid = (int)threadIdx.x;
    if (bid < nb) {
        const size_t tot = (size_t)NCOPY * (size_t)N;
        size_t i = (size_t)bid * 1024 + (size_t)tid * 4;
        if (i + 3 < tot) {
            *(ulonglong2*)&packed[i]     = make_ulonglong2(0ULL, 0ULL);
            *(ulonglong2*)&packed[i + 2] = make_ulonglong2(0ULL, 0ULL);
        } else {
            for (int k = 0; k < 4; ++k)
                if (i + k < tot) packed[i + k] = 0ULL;
        }
        return;
    }
    if (bid == nb) {
        unsigned m = 0;
        for (int i = 1 + 2 * tid; i < nwords; i += 512) m |= eiw[i];
        red[tid] = m;
        __syncthreads();
        for (int s = 128; s > 0; s >>= 1) {
            if (tid < s) red[tid] |= red[tid + s];
            __syncthreads();
        }
        if (tid == 0) mode[0] = (red[0] == 0) ? 1 : 0;
        return;
    }
    const int t_ = bid - nb - 1;  // 0..159
    if (t_ < 64) {
        int t = t_ * 256 + tid;            // 128x128
        int n = t / 128, k = t % 128;
        WT1[t] = (_Float16)W1[k * 128 + n];
    } else if (t_ < 128) {
        int t = (t_ - 64) * 256 + tid;
        int n = t / 128, k = t % 128;
        WT2[t] = (_Float16)W2[k * 128 + n];
    } else {
        int t = (t_ - 128) * 256 + tid;    // 128x64
        int n = t / 128, k = t % 128;
        WT3[t] = (_Float16)W3[k * 64 + n];
    }
}

// ---------------------------------------------------------------------------
// MFMA GEMM body (shared by fused kernels). v_mfma_f32_16x16x32_f16,
// 4 waves, 64 rows/block. W pre-transposed fp16 [M][128] in global.
// ---------------------------------------------------------------------------
template <int M, bool BN, typename TI>
__device__ __forceinline__ void gemm_body(int gbid, const TI* __restrict__ X,
                                          const _Float16* __restrict__ WTg,
                                          const float* __restrict__ sc,
                                          const float* __restrict__ sh,
                                          __half* __restrict__ Hout, int N,
                                          _Float16* WT /* LDS, M*136 */) {
    constexpr int CT = M / 16;
    constexpr int LDK = 136;

    for (int t = threadIdx.x; t < M * 16; t += 256) {
        int n = t / 16, seg = t % 16;
        *(half8*)&WT[n * LDK + seg * 8] = *(const half8*)&WTg[n * 128 + seg * 8];
    }
    __syncthreads();

    const int wave = (int)threadIdx.x >> 6;
    const int lane = (int)threadIdx.x & 63;
    const int qd = lane >> 4;
    const int ln = lane & 15;
    const int tile0 = gbid * 64 + wave * 16;
    int ar = tile0 + ln;
    if (ar >= N) ar = N - 1;  // clamp (stores guarded)

    half8 aF[4];
    const TI* xr = X + (size_t)ar * 128 + qd * 8;
#pragma unroll
    for (int kb = 0; kb < 4; ++kb) {
        float vv[8];
        if constexpr (sizeof(TI) == 4) {
            float4 v0 = *(const float4*)(xr + kb * 32);
            float4 v1 = *(const float4*)(xr + kb * 32 + 4);
            vv[0] = v0.x; vv[1] = v0.y; vv[2] = v0.z; vv[3] = v0.w;
            vv[4] = v1.x; vv[5] = v1.y; vv[6] = v1.z; vv[7] = v1.w;
        } else {
            half8 raw = *(const half8*)(xr + kb * 32);
#pragma unroll
            for (int j = 0; j < 8; ++j) vv[j] = (float)raw[j];
        }
        if (BN) {
            const int kbase = kb * 32 + qd * 8;
#pragma unroll
            for (int j = 0; j < 8; ++j)
                vv[j] = fmaxf(fmaf(vv[j], sc[kbase + j], sh[kbase + j]), 0.0f);
        }
        half8 a;
#pragma unroll
        for (int j = 0; j < 8; ++j) a[j] = (_Float16)vv[j];
        aF[kb] = a;
    }

#pragma unroll
    for (int ct = 0; ct < CT; ++ct) {
        floatx4 acc = {0.0f, 0.0f, 0.0f, 0.0f};
#pragma unroll
        for (int kb = 0; kb < 4; ++kb) {
            half8 b = *(const half8*)&WT[(ct * 16 + ln) * LDK + kb * 32 + qd * 8];
            acc = __builtin_amdgcn_mfma_f32_16x16x32_f16(aF[kb], b, acc, 0, 0, 0);
        }
#pragma unroll
        for (int r = 0; r < 4; ++r) {
            int orow = tile0 + qd * 4 + r;
            if (orow < N) Hout[(size_t)orow * M + ct * 16 + ln] = __float2half(acc[r]);
        }
    }
}

// ---------------------------------------------------------------------------
// Fused: [0,GB) = GEMM1 (x@W1 -> H, MFMA/LDS) ; [GB,..) = degree histogram
// into the per-XCD private copy with WORKGROUP-scope atomics -> the RMW
// executes in the local TCC (L2), never crossing the fabric. rank[e] carries
// (xcd << 24) | rank-within-copy.
// ---------------------------------------------------------------------------
__global__ __launch_bounds__(256) void hist_gemm1_kernel(const void* __restrict__ ei,
                                                         const float* __restrict__ ew,
                                                         unsigned long long* __restrict__ packed,
                                                         unsigned* __restrict__ rank,
                                                         const int* __restrict__ mode, int E, int GB,
                                                         const float* __restrict__ X,
                                                         const _Float16* __restrict__ WT1g,
                                                         __half* __restrict__ Hout, int N) {
    __shared__ _Float16 WT[128 * 136];
    if ((int)blockIdx.x < GB) {
        gemm_body<128, false, float>(blockIdx.x, X, WT1g, nullptr, nullptr, Hout, N, WT);
        return;
    }
    const int md = *mode;
    const unsigned xcc = xcc_id();
    unsigned long long* __restrict__ pb = packed + (size_t)xcc * (size_t)N;
    const int e = ((int)blockIdx.x - GB) * 1024 + (int)threadIdx.x * 4;
    if (e + 3 < E) {
        long long d0, d1, d2, d3;
        if (md) {
            const long long* p = (const long long*)ei + (long long)E + e;
            longlong2 a = *(const longlong2*)p;
            longlong2 b = *(const longlong2*)(p + 2);
            d0 = a.x; d1 = a.y; d2 = b.x; d3 = b.y;
        } else {
            const int* p = (const int*)ei + (long long)E + e;
            int4 a = *(const int4*)p;
            d0 = a.x; d1 = a.y; d2 = a.z; d3 = a.w;
        }
        float4 w4 = *(const float4*)(ew + e);
        unsigned long long o0 = __hip_atomic_fetch_add(
            &pb[d0], (1ULL << 40) | (unsigned long long)(w4.x * FPSCALE),
            __ATOMIC_RELAXED, __HIP_MEMORY_SCOPE_WORKGROUP);
        unsigned long long o1 = __hip_atomic_fetch_add(
            &pb[d1], (1ULL << 40) | (unsigned long long)(w4.y * FPSCALE),
            __ATOMIC_RELAXED, __HIP_MEMORY_SCOPE_WORKGROUP);
        unsigned long long o2 = __hip_atomic_fetch_add(
            &pb[d2], (1ULL << 40) | (unsigned long long)(w4.z * FPSCALE),
            __ATOMIC_RELAXED, __HIP_MEMORY_SCOPE_WORKGROUP);
        unsigned long long o3 = __hip_atomic_fetch_add(
            &pb[d3], (1ULL << 40) | (unsigned long long)(w4.w * FPSCALE),
            __ATOMIC_RELAXED, __HIP_MEMORY_SCOPE_WORKGROUP);
        uint4 r4;
        r4.x = (xcc << 24) | (unsigned)((o0 >> 40) & 0xFFFFFFu);
        r4.y = (xcc << 24) | (unsigned)((o1 >> 40) & 0xFFFFFFu);
        r4.z = (xcc << 24) | (unsigned)((o2 >> 40) & 0xFFFFFFu);
        r4.w = (xcc << 24) | (unsigned)((o3 >> 40) & 0xFFFFFFu);
        *(uint4*)(rank + e) = r4;
    } else {
#pragma unroll 1
        for (int k = 0; k < 4; ++k) {
            int ee = e + k;
            if (ee >= E) break;
            int d = load_edge(ei, md, (long long)E + ee);
            unsigned long long contrib =
                (1ULL << 40) | (unsigned long long)(ew[ee] * FPSCALE);
            unsigned long long old = __hip_atomic_fetch_add(
                &pb[d], contrib, __ATOMIC_RELAXED, __HIP_MEMORY_SCOPE_WORKGROUP);
            rank[ee] = (xcc << 24) | (unsigned)((old >> 40) & 0xFFFFFFu);
        }
    }
}

// ---------------------------------------------------------------------------
// unpack: per node sum the NCOPY copies -> (cnt, dinv), per-copy exclusive
// prefix -> coff[node*8+c]; plus per-2048-chunk sum (scanA) in one pass.
// ---------------------------------------------------------------------------
__global__ __launch_bounds__(256) void unpack_scanA_kernel(const unsigned long long* __restrict__ packed,
                                                           float* __restrict__ dinv,
                                                           int* __restrict__ cnt,
                                                           unsigned* __restrict__ coff,
                                                           int* __restrict__ bsum, int N) {
    __shared__ int red[256];
    const int tid = (int)threadIdx.x;
    const int base = (int)blockIdx.x * 2048 + tid * 8;
    int s = 0;
#pragma unroll
    for (int j = 0; j < 8; ++j) {
        int idx = base + j;
        if (idx < N) {
            unsigned long long wsum = 0ULL;
            unsigned pref = 0;
#pragma unroll
            for (int c = 0; c < NCOPY; ++c) {
                unsigned long long p = packed[(size_t)c * N + idx];
                coff[(size_t)idx * NCOPY + c] = pref;
                pref += (unsigned)(p >> 40);
                wsum += (p & 0xFFFFFFFFFFULL);
            }
            cnt[idx] = (int)pref;
            dinv[idx] = rsqrtf(1.0f + (float)wsum * (1.0f / FPSCALE));
            s += (int)pref;
        }
    }
    red[tid] = s;
    __syncthreads();
    for (int st = 128; st > 0; st >>= 1) {
        if (tid < st) red[tid] += red[tid + st];
        __syncthreads();
    }
    if (tid == 0) bsum[blockIdx.x] = red[0];
}

// row_start: local exclusive scan + direct sum over bsum[0..bid) (G<=64, cheap)
__global__ __launch_bounds__(256) void scanC_kernel(const int* __restrict__ cnt,
                                                    const int* __restrict__ bsum,
                                                    int* __restrict__ row_start, int N) {
    __shared__ int lds[256];
    const int tid = (int)threadIdx.x;
    int gbase = 0;
    for (int j = 0; j < (int)blockIdx.x; ++j) gbase += bsum[j];
    const int base = (int)blockIdx.x * 2048 + tid * 8;
    int vals[8];
    int s = 0;
#pragma unroll
    for (int j = 0; j < 8; ++j) {
        int idx = base + j;
        int v = (idx < N) ? cnt[idx] : 0;
        vals[j] = s;
        s += v;
    }
    lds[tid] = s;
    __syncthreads();
    for (int off = 1; off < 256; off <<= 1) {
        int t = 0;
        if (tid >= off) t = lds[tid - off];
        __syncthreads();
        lds[tid] += t;
        __syncthreads();
    }
    int excl = lds[tid] - s;
    int b = gbase + excl;
#pragma unroll
    for (int j = 0; j < 8; ++j) {
        int idx = base + j;
        if (idx < N) row_start[idx] = b + vals[j];
    }
}

// ---------------------------------------------------------------------------
// Atomic-free scatter (slot = row_start[d] + coff[d][xcd] + rank, 4B payload)
// + last block zeroes the BN stats accumulators for layer 1. Slot clamped to
// [0,E) as insurance (no-op when counts are consistent).
// ---------------------------------------------------------------------------
__global__ __launch_bounds__(256) void scatter_zero_kernel(const void* __restrict__ ei,
                                                           const float* __restrict__ ew,
                                                           const float* __restrict__ dinv,
                                                           const int* __restrict__ row_start,
                                                           const unsigned* __restrict__ rank,
                                                           const unsigned* __restrict__ coff,
                                                           unsigned* __restrict__ edata,
                                                           const int* __restrict__ mode, int E, int EBK,
                                                           float* __restrict__ gsum,
                                                           float* __restrict__ gsq) {
    if ((int)blockIdx.x == EBK) {
        if (threadIdx.x < 128) { gsum[threadIdx.x] = 0.0f; gsq[threadIdx.x] = 0.0f; }
        return;
    }
    int e = (int)blockIdx.x * 256 + (int)threadIdx.x;
    if (e >= E) return;
    int md = *mode;
    int s = load_edge(ei, md, e);
    int d = load_edge(ei, md, (long long)E + e);
    float wn = dinv[s] * ew[e] * dinv[d];
    unsigned hb = (unsigned)__half_as_ushort(__float2half(wn)) & 0x7fffu;
    unsigned r = rank[e];
    unsigned c = r >> 24;
    int slot = row_start[d] + (int)coff[(size_t)d * NCOPY + c] + (int)(r & 0xFFFFFFu);
    slot = min(max(slot, 0), E - 1);
    edata[slot] = ((unsigned)s << 15) | hb;
}

// ---------------------------------------------------------------------------
// CSR aggregation v2: one WAVE per node (4 nodes / 256-thr block). No LDS, no
// barriers: each lane holds one edge word, broadcast via __shfl; 8-deep
// unrolled gathers; zero-padded tail (pad word 0 -> src 0, wn 0).
// ---------------------------------------------------------------------------
template <int D, bool BIAS, typename TY>
__global__ __launch_bounds__(256) void agg_kernel(const __half* __restrict__ H,
                                                  const unsigned* __restrict__ edata,
                                                  const int* __restrict__ row_start,
                                                  const int* __restrict__ cnt,
                                                  const float* __restrict__ dinv,
                                                  const float* __restrict__ bias,
                                                  TY* __restrict__ Y, int N) {
    constexpr int VPT = D / 64;  // 2 (D=128) or 1 (D=64)
    const int lane = (int)threadIdx.x & 63;
    const int i = (int)blockIdx.x * 4 + ((int)threadIdx.x >> 6);
    if (i >= N) return;
    const int c0 = lane * VPT;
    const float di = dinv[i];
    const float dii = di * di;

    float acc0, acc1 = 0.0f;
    if constexpr (VPT == 2) {
        float2 h = load2(H + (size_t)i * D + c0);
        acc0 = dii * h.x;
        acc1 = dii * h.y;
    } else {
        acc0 = dii * loadS(H + (size_t)i * D + c0);
    }

    const int base = row_start[i];
    const int n = cnt[i];
    for (int off = 0; off < n; off += 64) {
        const int rem = n - off;
        unsigned ev = 0;
        if (lane < rem) ev = edata[base + off + lane];
        const int mm = min(64, rem);
        for (int j = 0; j < mm; j += 8) {
            const unsigned e0 = __shfl(ev, j),     e1 = __shfl(ev, j + 1);
            const unsigned e2 = __shfl(ev, j + 2), e3 = __shfl(ev, j + 3);
            const unsigned e4 = __shfl(ev, j + 4), e5 = __shfl(ev, j + 5);
            const unsigned e6 = __shfl(ev, j + 6), e7 = __shfl(ev, j + 7);
            if constexpr (VPT == 2) {
                float2 h0 = load2(H + (size_t)(e0 >> 15) * D + c0);
                float2 h1 = load2(H + (size_t)(e1 >> 15) * D + c0);
                float2 h2 = load2(H + (size_t)(e2 >> 15) * D + c0);
                float2 h3 = load2(H + (size_t)(e3 >> 15) * D + c0);
                float2 h4 = load2(H + (size_t)(e4 >> 15) * D + c0);
                float2 h5 = load2(H + (size_t)(e5 >> 15) * D + c0);
                float2 h6 = load2(H + (size_t)(e6 >> 15) * D + c0);
                float2 h7 = load2(H + (size_t)(e7 >> 15) * D + c0);
                acc0 = fmaf(wn_of(e0), h0.x, acc0); acc1 = fmaf(wn_of(e0), h0.y, acc1);
                acc0 = fmaf(wn_of(e1), h1.x, acc0); acc1 = fmaf(wn_of(e1), h1.y, acc1);
                acc0 = fmaf(wn_of(e2), h2.x, acc0); acc1 = fmaf(wn_of(e2), h2.y, acc1);
                acc0 = fmaf(wn_of(e3), h3.x, acc0); acc1 = fmaf(wn_of(e3), h3.y, acc1);
                acc0 = fmaf(wn_of(e4), h4.x, acc0); acc1 = fmaf(wn_of(e4), h4.y, acc1);
                acc0 = fmaf(wn_of(e5), h5.x, acc0); acc1 = fmaf(wn_of(e5), h5.y, acc1);
                acc0 = fmaf(wn_of(e6), h6.x, acc0); acc1 = fmaf(wn_of(e6), h6.y, acc1);
                acc0 = fmaf(wn_of(e7), h7.x, acc0); acc1 = fmaf(wn_of(e7), h7.y, acc1);
            } else {
                float h0 = loadS(H + (size_t)(e0 >> 15) * D + c0);
                float h1 = loadS(H + (size_t)(e1 >> 15) * D + c0);
                float h2 = loadS(H + (size_t)(e2 >> 15) * D + c0);
                float h3 = loadS(H + (size_t)(e3 >> 15) * D + c0);
                float h4 = loadS(H + (size_t)(e4 >> 15) * D + c0);
                float h5 = loadS(H + (size_t)(e5 >> 15) * D + c0);
                float h6 = loadS(H + (size_t)(e6 >> 15) * D + c0);
                float h7 = loadS(H + (size_t)(e7 >> 15) * D + c0);
                acc0 = fmaf(wn_of(e0), h0, acc0);
                acc0 = fmaf(wn_of(e1), h1, acc0);
                acc0 = fmaf(wn_of(e2), h2, acc0);
                acc0 = fmaf(wn_of(e3), h3, acc0);
                acc0 = fmaf(wn_of(e4), h4, acc0);
                acc0 = fmaf(wn_of(e5), h5, acc0);
                acc0 = fmaf(wn_of(e6), h6, acc0);
                acc0 = fmaf(wn_of(e7), h7, acc0);
            }
        }
    }

    if constexpr (VPT == 2) {
        if (BIAS) { acc0 += bias[c0]; acc1 += bias[c0 + 1]; }
        store2(Y + (size_t)i * D + c0, acc0, acc1);
    } else {
        if (BIAS) acc0 += bias[c0];
        storeS(Y + (size_t)i * D + c0, acc0);
    }
}

// ---------------------------------------------------------------------------
// GEMM dispatch wrapper; optional extra block zeroes next layer's BN stats.
// ---------------------------------------------------------------------------
template <int M, bool BN, typename TI, bool ZERO>
__global__ __launch_bounds__(256) void gemm_mfma_kernel(const TI* __restrict__ X,
                                                        const _Float16* __restrict__ WTg,
                                                        const float* __restrict__ sc,
                                                        const float* __restrict__ sh,
                                                        __half* __restrict__ Hout, int N,
                                                        float* __restrict__ gsum,
                                                        float* __restrict__ gsq, int GB) {
    __shared__ _Float16 WT[M * 136];
    if (ZERO && (int)blockIdx.x == GB) {
        if (threadIdx.x < 128) { gsum[threadIdx.x] = 0.0f; gsq[threadIdx.x] = 0.0f; }
        return;
    }
    gemm_body<M, BN, TI>(blockIdx.x, X, WTg, sc, sh, Hout, N, WT);
}

// ---------------------------------------------------------------------------
// BatchNorm statistics (fp16 Y)
// ---------------------------------------------------------------------------
__global__ void stats_kernel(const __half* __restrict__ Y, float* __restrict__ gsum,
                             float* __restrict__ gsq, int N) {
    __shared__ float ls[256], lq[256];
    const int tid = threadIdx.x;
    const int c = tid & 127;
    const int half_ = tid >> 7;
    float s = 0.0f, q = 0.0f;
    for (int row = blockIdx.x * 2 + half_; row < N; row += 512) {
        float v = __half2float(Y[(size_t)row * 128 + c]);
        s += v;
        q = fmaf(v, v, q);
    }
    ls[tid] = s; lq[tid] = q;
    __syncthreads();
    if (tid < 128) {
        atomicAdd(&gsum[c], ls[tid] + ls[tid + 128]);
        atomicAdd(&gsq[c],  lq[tid] + lq[tid + 128]);
    }
}

__global__ void finalize_stats_kernel(const float* __restrict__ gsum, const float* __restrict__ gsq,
                                      const float* __restrict__ gamma, const float* __restrict__ beta,
                                      float* __restrict__ sc, float* __restrict__ sh, int N) {
    int t = threadIdx.x;
    if (t < 128) {
        float inv_n = 1.0f / (float)N;
        float mean = gsum[t] * inv_n;
        float var = gsq[t] * inv_n - mean * mean;
        float scale = gamma[t] * rsqrtf(var + BN_EPS);
        sc[t] = scale;
        sh[t] = beta[t] - mean * scale;
    }
}

// ---------------------------------------------------------------------------
// Launch
// ---------------------------------------------------------------------------
extern "C" void kernel_launch(void* const* d_in, const int* in_sizes, int n_in,
                              void* d_out, int out_size, void* d_ws, size_t ws_size,
                              hipStream_t stream) {
    const float* x   = (const float*)d_in[0];
    const void*  ei  = d_in[1];
    const float* ew  = (const float*)d_in[2];
    const float* W1  = (const float*)d_in[3];
    const float* W2  = (const float*)d_in[5];
    const float* W3  = (const float*)d_in[7];
    const float* b3  = (const float*)d_in[8];
    const float* g1  = (const float*)d_in[9];
    const float* be1 = (const float*)d_in[10];
    const float* g2  = (const float*)d_in[11];
    const float* be2 = (const float*)d_in[12];
    float* out = (float*)d_out;

    const int N = in_sizes[0] / 128;   // 100000 (edge packing needs N <= 2^17)
    const int E = in_sizes[2];
    const int G = (N + 2047) / 2048;

    char* w = (char*)d_ws;
    size_t off = 0;
    auto alloc = [&](size_t bytes) -> void* {
        void* p = w + off;
        off += (bytes + 255) & ~(size_t)255;
        return p;
    };
    unsigned long long* packed = (unsigned long long*)alloc((size_t)NCOPY * N * 8);
    float* dinv      = (float*)alloc((size_t)N * 4);
    int*   cnt       = (int*)  alloc((size_t)N * 4);
    int*   row_start = (int*)  alloc((size_t)N * 4);
    unsigned* rank   = (unsigned*)alloc((size_t)E * 4);
    unsigned* edata  = (unsigned*)alloc((size_t)E * 4);
    unsigned* coff   = (unsigned*)alloc((size_t)N * NCOPY * 4);
    int*   bsum      = (int*)  alloc((size_t)G * 4);
    int*   mode      = (int*)  alloc(256);
    float* gsum      = (float*)alloc(128 * 4);
    float* gsq       = (float*)alloc(128 * 4);
    float* scb       = (float*)alloc(128 * 4);
    float* shb       = (float*)alloc(128 * 4);
    _Float16* WT1    = (_Float16*)alloc(128 * 128 * 2);
    _Float16* WT2    = (_Float16*)alloc(128 * 128 * 2);
    _Float16* WT3    = (_Float16*)alloc(128 * 64 * 2);
    __half* H        = (__half*)alloc((size_t)N * 128 * 2);  // gemm out / agg in
    __half* Yh       = (__half*)alloc((size_t)N * 128 * 2);  // agg out / next gemm in
    (void)ws_size; (void)n_in; (void)out_size;

    const int nbz = (int)(((size_t)NCOPY * N + 1023) / 1024);  // zero blocks (4 u64/thread)
    const int ebk = (E + 255) / 256;
    const int ehb = (E + 1023) / 1024;   // hist blocks: 4 edges/thread
    const int gb  = (N + 63) / 64;
    const int ab  = (N + 3) / 4;

    // 1: zero hist copies + detect dtype + W transposes (all independent)
    init_kernel<<<nbz + 1 + 160, 256, 0, stream>>>((const unsigned*)ei, 4096, mode, packed, N,
                                                   W1, W2, W3, WT1, WT2, WT3, nbz);
    // 2: GEMM1 (MFMA-bound) fused with per-XCD L2-local histogram — overlap
    hist_gemm1_kernel<<<gb + ehb, 256, 0, stream>>>(ei, ew, packed, rank, mode, E, gb,
                                                    x, WT1, H, N);
    // 3-4: unpack (merge copies, coff) + scan -> row_start
    unpack_scanA_kernel<<<G, 256, 0, stream>>>(packed, dinv, cnt, coff, bsum, N);
    scanC_kernel<<<G, 256, 0, stream>>>(cnt, bsum, row_start, N);
    // 5: atomic-free scatter (+ zero BN stats for L1)
    scatter_zero_kernel<<<ebk + 1, 256, 0, stream>>>(ei, ew, dinv, row_start, rank, coff, edata,
                                                     mode, E, ebk, gsum, gsq);

    // ---- L1: Yh = Ahat*H ----
    agg_kernel<128, false, __half><<<ab, 256, 0, stream>>>(H, edata, row_start, cnt, dinv, nullptr, Yh, N);
    stats_kernel<<<256, 256, 0, stream>>>(Yh, gsum, gsq, N);
    finalize_stats_kernel<<<1, 128, 0, stream>>>(gsum, gsq, g1, be1, scb, shb, N);

    // ---- L2: H = relu(bn(Yh))@W2 ; Yh = Ahat*H ----
    gemm_mfma_kernel<128, true, __half, true><<<gb + 1, 256, 0, stream>>>(Yh, WT2, scb, shb, H, N, gsum, gsq, gb);
    agg_kernel<128, false, __half><<<ab, 256, 0, stream>>>(H, edata, row_start, cnt, dinv, nullptr, Yh, N);
    stats_kernel<<<256, 256, 0, stream>>>(Yh, gsum, gsq, N);
    finalize_stats_kernel<<<1, 128, 0, stream>>>(gsum, gsq, g2, be2, scb, shb, N);

    // ---- L3: H64 = relu(bn(Yh))@W3 ; out = Ahat*H64 + b3 ----
    gemm_mfma_kernel<64, true, __half, false><<<gb, 256, 0, stream>>>(Yh, WT3, scb, shb, H, N, nullptr, nullptr, gb);
    agg_kernel<64, true, float><<<ab, 256, 0, stream>>>(H, edata, row_start, cnt, dinv, b3, out, N);
}

// Round 4
// 498.855 us; speedup vs baseline: 1.1662x; 1.1491x over previous
//
#include <hip/hip_runtime.h>
#include <hip/hip_fp16.h>
#include <cstdint>
#include <cstddef>

#define BN_EPS 1e-5f
#define KB 256        // edge-chunk blocks for coarse hist / scatter (fixed)
#define BSH 9         // 512 nodes per coarse bucket; requires N <= 131072

typedef _Float16 half8 __attribute__((ext_vector_type(8)));
typedef float floatx4 __attribute__((ext_vector_type(4)));

// ---------------------------------------------------------------------------
// fp16 helpers
// ---------------------------------------------------------------------------
__device__ __forceinline__ float loadS(const __half* p) { return __half2float(*p); }
__device__ __forceinline__ float2 load2(const __half* p) {
    return __half22float2(*(const __half2*)p);
}
__device__ __forceinline__ void storeS(float* p, float v) { *p = v; }
__device__ __forceinline__ void storeS(__half* p, float v) { *p = __float2half(v); }
__device__ __forceinline__ void store2(float* p, float a, float b) {
    *(float2*)p = make_float2(a, b);
}
__device__ __forceinline__ void store2(__half* p, float a, float b) {
    *(__half2*)p = __floats2half2_rn(a, b);
}
// packed edge word: (src << 15) | fp16 bits of (ew * dinv[dst]), sign stripped.
// word 0 => src 0, weight 0 (safe padding).
__device__ __forceinline__ float wn_of(unsigned v) {
    __half_raw hr; hr.x = (unsigned short)(v & 0x7fffu);
    return __half2float((__half)hr);
}

static __device__ __forceinline__ int load_edge(const void* ei, int mode64, long long pos) {
    if (mode64) return (int)((const long long*)ei)[pos];
    return ((const int*)ei)[pos];
}

// ---------------------------------------------------------------------------
// init: [0,64) zero pc[256][256] | block 64: detect int64-vs-int32 | rest:
// W->WT fp16 transposes
// ---------------------------------------------------------------------------
__global__ __launch_bounds__(256) void init_kernel(const unsigned* __restrict__ eiw, int nwords,
                                                   int* __restrict__ mode,
                                                   unsigned* __restrict__ pc,
                                                   const float* __restrict__ W1,
                                                   const float* __restrict__ W2,
                                                   const float* __restrict__ W3,
                                                   _Float16* __restrict__ WT1,
                                                   _Float16* __restrict__ WT2,
                                                   _Float16* __restrict__ WT3) {
    __shared__ unsigned red[256];
    const int bid = (int)blockIdx.x;
    const int tid = (int)threadIdx.x;
    if (bid < 64) {  // zero 256*256 u32
        uint4 z = make_uint4(0, 0, 0, 0);
        *(uint4*)&pc[bid * 1024 + tid * 4] = z;
        return;
    }
    if (bid == 64) {
        unsigned m = 0;
        for (int i = 1 + 2 * tid; i < nwords; i += 512) m |= eiw[i];
        red[tid] = m;
        __syncthreads();
        for (int s = 128; s > 0; s >>= 1) {
            if (tid < s) red[tid] |= red[tid + s];
            __syncthreads();
        }
        if (tid == 0) mode[0] = (red[0] == 0) ? 1 : 0;
        return;
    }
    const int t_ = bid - 65;  // 0..159
    if (t_ < 64) {
        int t = t_ * 256 + tid;            // 128x128
        int n = t / 128, k = t % 128;
        WT1[t] = (_Float16)W1[k * 128 + n];
    } else if (t_ < 128) {
        int t = (t_ - 64) * 256 + tid;
        int n = t / 128, k = t % 128;
        WT2[t] = (_Float16)W2[k * 128 + n];
    } else {
        int t = (t_ - 128) * 256 + tid;    // 128x64
        int n = t / 128, k = t % 128;
        WT3[t] = (_Float16)W3[k * 64 + n];
    }
}

// ---------------------------------------------------------------------------
// P1: coarse histogram. Each block owns one edge chunk; LDS histogram over
// coarse buckets (d>>BSH); writes per-(block,bucket) counts.
// ---------------------------------------------------------------------------
__global__ __launch_bounds__(256) void coarse_hist_kernel(const void* __restrict__ ei,
                                                          const int* __restrict__ mode,
                                                          unsigned* __restrict__ pc,
                                                          int E, int epb) {
    __shared__ unsigned h[256];
    const int k = (int)blockIdx.x;
    const int tid = (int)threadIdx.x;
    h[tid] = 0;
    __syncthreads();
    const int md = *mode;
    const int e0 = k * epb;
    const int e1 = min(E, e0 + epb);
    for (int e = e0 + tid; e < e1; e += 256) {
        int d = load_edge(ei, md, (long long)E + e);
        atomicAdd(&h[d >> BSH], 1u);
    }
    __syncthreads();
    pc[k * 256 + tid] = h[tid];
}

// ---------------------------------------------------------------------------
// P2a: per-bucket exclusive scan over the KB blocks (in-place on pc),
// bucket totals -> tb. Grid = nbuck blocks.
// ---------------------------------------------------------------------------
__global__ __launch_bounds__(256) void scan_pc_kernel(unsigned* __restrict__ pc,
                                                      int* __restrict__ tb) {
    __shared__ int red[256];
    const int b = (int)blockIdx.x;
    const int tid = (int)threadIdx.x;
    const unsigned v = pc[tid * 256 + b];
    red[tid] = (int)v;
    __syncthreads();
    for (int off = 1; off < 256; off <<= 1) {
        int t = 0;
        if (tid >= off) t = red[tid - off];
        __syncthreads();
        red[tid] += t;
        __syncthreads();
    }
    pc[tid * 256 + b] = (unsigned)(red[tid] - (int)v);
    if (tid == 255) tb[b] = red[255];
}

// ---------------------------------------------------------------------------
// P2b: exclusive scan of bucket totals -> bucket_base (all 256 entries;
// beyond nbuck => E). Also zeroes BN stats accumulators for layer 1.
// ---------------------------------------------------------------------------
__global__ __launch_bounds__(256) void scan_buckets_kernel(const int* __restrict__ tb,
                                                           int* __restrict__ bbase, int nbuck,
                                                           float* __restrict__ gsum,
                                                           float* __restrict__ gsq) {
    __shared__ int red[256];
    const int tid = (int)threadIdx.x;
    const int v = (tid < nbuck) ? tb[tid] : 0;
    red[tid] = v;
    __syncthreads();
    for (int off = 1; off < 256; off <<= 1) {
        int t = 0;
        if (tid >= off) t = red[tid - off];
        __syncthreads();
        red[tid] += t;
        __syncthreads();
    }
    bbase[tid] = red[tid] - v;
    if (tid < 128) { gsum[tid] = 0.0f; gsq[tid] = 0.0f; }
}

// ---------------------------------------------------------------------------
// MFMA GEMM body. v_mfma_f32_16x16x32_f16, 4 waves, 64 rows/block.
// W pre-transposed fp16 [M][128] in global, staged to LDS.
// ---------------------------------------------------------------------------
template <int M, bool BN, typename TI>
__device__ __forceinline__ void gemm_body(int gbid, const TI* __restrict__ X,
                                          const _Float16* __restrict__ WTg,
                                          const float* __restrict__ sc,
                                          const float* __restrict__ sh,
                                          __half* __restrict__ Hout, int N,
                                          _Float16* WT /* LDS, M*136 */) {
    constexpr int CT = M / 16;
    constexpr int LDK = 136;

    for (int t = threadIdx.x; t < M * 16; t += 256) {
        int n = t / 16, seg = t % 16;
        *(half8*)&WT[n * LDK + seg * 8] = *(const half8*)&WTg[n * 128 + seg * 8];
    }
    __syncthreads();

    const int wave = (int)threadIdx.x >> 6;
    const int lane = (int)threadIdx.x & 63;
    const int qd = lane >> 4;
    const int ln = lane & 15;
    const int tile0 = gbid * 64 + wave * 16;
    int ar = tile0 + ln;
    if (ar >= N) ar = N - 1;  // clamp (stores guarded)

    half8 aF[4];
    const TI* xr = X + (size_t)ar * 128 + qd * 8;
#pragma unroll
    for (int kb = 0; kb < 4; ++kb) {
        float vv[8];
        if constexpr (sizeof(TI) == 4) {
            float4 v0 = *(const float4*)(xr + kb * 32);
            float4 v1 = *(const float4*)(xr + kb * 32 + 4);
            vv[0] = v0.x; vv[1] = v0.y; vv[2] = v0.z; vv[3] = v0.w;
            vv[4] = v1.x; vv[5] = v1.y; vv[6] = v1.z; vv[7] = v1.w;
        } else {
            half8 raw = *(const half8*)(xr + kb * 32);
#pragma unroll
            for (int j = 0; j < 8; ++j) vv[j] = (float)raw[j];
        }
        if (BN) {
            const int kbase = kb * 32 + qd * 8;
#pragma unroll
            for (int j = 0; j < 8; ++j)
                vv[j] = fmaxf(fmaf(vv[j], sc[kbase + j], sh[kbase + j]), 0.0f);
        }
        half8 a;
#pragma unroll
        for (int j = 0; j < 8; ++j) a[j] = (_Float16)vv[j];
        aF[kb] = a;
    }

#pragma unroll
    for (int ct = 0; ct < CT; ++ct) {
        floatx4 acc = {0.0f, 0.0f, 0.0f, 0.0f};
#pragma unroll
        for (int kb = 0; kb < 4; ++kb) {
            half8 b = *(const half8*)&WT[(ct * 16 + ln) * LDK + kb * 32 + qd * 8];
            acc = __builtin_amdgcn_mfma_f32_16x16x32_f16(aF[kb], b, acc, 0, 0, 0);
        }
#pragma unroll
        for (int r = 0; r < 4; ++r) {
            int orow = tile0 + qd * 4 + r;
            if (orow < N) Hout[(size_t)orow * M + ct * 16 + ln] = __float2half(acc[r]);
        }
    }
}

// ---------------------------------------------------------------------------
// P3 fused with GEMM1: [0,GB) = GEMM1 (x@W1 -> H) ; [GB,GB+KB) = bucket
// scatter. Replays the coarse histogram with LDS atomics; every edge gets a
// unique slot in bucket-sorted order. payload u64 = d:17 | src:17 | ew_fp16.
// No global atomics anywhere.
// ---------------------------------------------------------------------------
__global__ __launch_bounds__(256) void sort_gemm1_kernel(const void* __restrict__ ei,
                                                         const float* __restrict__ ew,
                                                         const unsigned* __restrict__ pc,
                                                         const int* __restrict__ bbase,
                                                         unsigned long long* __restrict__ sortedE,
                                                         const int* __restrict__ mode, int E,
                                                         int epb, int GB,
                                                         const float* __restrict__ X,
                                                         const _Float16* __restrict__ WT1g,
                                                         __half* __restrict__ Hout, int N) {
    __shared__ _Float16 WT[128 * 136];
    __shared__ unsigned off_s[256];
    if ((int)blockIdx.x < GB) {
        gemm_body<128, false, float>(blockIdx.x, X, WT1g, nullptr, nullptr, Hout, N, WT);
        return;
    }
    const int k = (int)blockIdx.x - GB;
    const int tid = (int)threadIdx.x;
    off_s[tid] = (unsigned)bbase[tid] + pc[k * 256 + tid];
    __syncthreads();
    const int md = *mode;
    const int e0 = k * epb;
    const int e1 = min(E, e0 + epb);
    for (int e = e0 + tid; e < e1; e += 256) {
        int d = load_edge(ei, md, (long long)E + e);
        int s = load_edge(ei, md, e);
        float wv = ew[e];
        unsigned slot = atomicAdd(&off_s[d >> BSH], 1u);
        sortedE[slot] = ((unsigned long long)(unsigned)d << 33) |
                        ((unsigned long long)(unsigned)s << 16) |
                        (unsigned long long)(unsigned short)__half_as_ushort(__float2half(wv));
    }
}

// ---------------------------------------------------------------------------
// P4: per-bucket CSR build. Bucket = 512 consecutive nodes; its edges are a
// contiguous run of sortedE. LDS: fine counts + fp32 weight sums (pass 1),
// LDS scan -> cnt/dinv/row_start, pass 2 writes edata (unique rank via LDS
// atomic; order-unstable, sum-commutative => valid).
// ---------------------------------------------------------------------------
__global__ __launch_bounds__(256) void csr_build_kernel(const unsigned long long* __restrict__ sortedE,
                                                        const int* __restrict__ bbase,
                                                        const int* __restrict__ tb,
                                                        float* __restrict__ dinv,
                                                        int* __restrict__ cnt,
                                                        int* __restrict__ row_start,
                                                        unsigned* __restrict__ edata, int N) {
    __shared__ unsigned cs[512];
    __shared__ float ws[512];
    __shared__ float dv[512];
    __shared__ unsigned sc[512];
    __shared__ unsigned cur[512];
    __shared__ int red[256];
    const int b = (int)blockIdx.x;
    const int tid = (int)threadIdx.x;
    const int n0 = b << BSH;
    const int base = bbase[b];
    const int len = tb[b];

    cs[tid] = 0; cs[tid + 256] = 0;
    ws[tid] = 0.0f; ws[tid + 256] = 0.0f;
    cur[tid] = 0; cur[tid + 256] = 0;
    __syncthreads();

    for (int i = tid; i < len; i += 256) {
        unsigned long long p = sortedE[base + i];
        unsigned fine = (unsigned)(p >> 33) - (unsigned)n0;
        atomicAdd(&cs[fine], 1u);
        __half_raw hr; hr.x = (unsigned short)(p & 0xFFFFu);
        atomicAdd(&ws[fine], __half2float((__half)hr));
    }
    __syncthreads();

    // exclusive scan of cs over 512 bins (pair per thread)
    const unsigned a0 = cs[2 * tid];
    const unsigned a1 = cs[2 * tid + 1];
    const int s2 = (int)(a0 + a1);
    red[tid] = s2;
    __syncthreads();
    for (int off = 1; off < 256; off <<= 1) {
        int t = 0;
        if (tid >= off) t = red[tid - off];
        __syncthreads();
        red[tid] += t;
        __syncthreads();
    }
    const int excl2 = red[tid] - s2;
    sc[2 * tid] = (unsigned)excl2;
    sc[2 * tid + 1] = (unsigned)(excl2 + (int)a0);

#pragma unroll
    for (int q = 0; q < 2; ++q) {
        const int f = tid + q * 256;
        const int node = n0 + f;
        const float dvv = rsqrtf(1.0f + ws[f]);  // self-loop weight 1 included
        dv[f] = dvv;
        if (node < N) {
            dinv[node] = dvv;
            cnt[node] = (int)cs[f];
            row_start[node] = base + (int)sc[f];
        }
    }
    __syncthreads();

    for (int i = tid; i < len; i += 256) {
        unsigned long long p = sortedE[base + i];
        unsigned fine = (unsigned)(p >> 33) - (unsigned)n0;
        unsigned s = (unsigned)(p >> 16) & 0x1FFFFu;
        __half_raw hr; hr.x = (unsigned short)(p & 0xFFFFu);
        float wnp = __half2float((__half)hr) * dv[fine];  // ew * dinv[dst]
        unsigned r = atomicAdd(&cur[fine], 1u);
        unsigned hb = (unsigned)__half_as_ushort(__float2half(wnp)) & 0x7fffu;
        edata[base + (int)sc[fine] + (int)r] = (s << 15) | hb;
    }
}

// ---------------------------------------------------------------------------
// CSR aggregation: one WAVE per node (4 nodes / 256-thr block). edata holds
// (src, ew*dinv[dst]); the dinv[src] factor is a broadcast load (all lanes
// same address). Self-loop: dinv[i]^2 * h[i].
// ---------------------------------------------------------------------------
template <int D, bool BIAS, typename TY>
__global__ __launch_bounds__(256) void agg_kernel(const __half* __restrict__ H,
                                                  const unsigned* __restrict__ edata,
                                                  const int* __restrict__ row_start,
                                                  const int* __restrict__ cnt,
                                                  const float* __restrict__ dinv,
                                                  const float* __restrict__ bias,
                                                  TY* __restrict__ Y, int N) {
    constexpr int VPT = D / 64;  // 2 (D=128) or 1 (D=64)
    const int lane = (int)threadIdx.x & 63;
    const int i = (int)blockIdx.x * 4 + ((int)threadIdx.x >> 6);
    if (i >= N) return;
    const int c0 = lane * VPT;
    const float di = dinv[i];
    const float dii = di * di;

    float acc0, acc1 = 0.0f;
    if constexpr (VPT == 2) {
        float2 h = load2(H + (size_t)i * D + c0);
        acc0 = dii * h.x;
        acc1 = dii * h.y;
    } else {
        acc0 = dii * loadS(H + (size_t)i * D + c0);
    }

    const int base = row_start[i];
    const int n = cnt[i];
    for (int off = 0; off < n; off += 64) {
        const int rem = n - off;
        unsigned ev = 0;
        if (lane < rem) ev = edata[base + off + lane];
        const int mm = min(64, rem);
        for (int j = 0; j < mm; j += 8) {
            const unsigned e0 = __shfl(ev, j),     e1 = __shfl(ev, j + 1);
            const unsigned e2 = __shfl(ev, j + 2), e3 = __shfl(ev, j + 3);
            const unsigned e4 = __shfl(ev, j + 4), e5 = __shfl(ev, j + 5);
            const unsigned e6 = __shfl(ev, j + 6), e7 = __shfl(ev, j + 7);
            const float w0 = dinv[e0 >> 15] * wn_of(e0);
            const float w1 = dinv[e1 >> 15] * wn_of(e1);
            const float w2 = dinv[e2 >> 15] * wn_of(e2);
            const float w3 = dinv[e3 >> 15] * wn_of(e3);
            const float w4 = dinv[e4 >> 15] * wn_of(e4);
            const float w5 = dinv[e5 >> 15] * wn_of(e5);
            const float w6 = dinv[e6 >> 15] * wn_of(e6);
            const float w7 = dinv[e7 >> 15] * wn_of(e7);
            if constexpr (VPT == 2) {
                float2 h0 = load2(H + (size_t)(e0 >> 15) * D + c0);
                float2 h1 = load2(H + (size_t)(e1 >> 15) * D + c0);
                float2 h2 = load2(H + (size_t)(e2 >> 15) * D + c0);
                float2 h3 = load2(H + (size_t)(e3 >> 15) * D + c0);
                float2 h4 = load2(H + (size_t)(e4 >> 15) * D + c0);
                float2 h5 = load2(H + (size_t)(e5 >> 15) * D + c0);
                float2 h6 = load2(H + (size_t)(e6 >> 15) * D + c0);
                float2 h7 = load2(H + (size_t)(e7 >> 15) * D + c0);
                acc0 = fmaf(w0, h0.x, acc0); acc1 = fmaf(w0, h0.y, acc1);
                acc0 = fmaf(w1, h1.x, acc0); acc1 = fmaf(w1, h1.y, acc1);
                acc0 = fmaf(w2, h2.x, acc0); acc1 = fmaf(w2, h2.y, acc1);
                acc0 = fmaf(w3, h3.x, acc0); acc1 = fmaf(w3, h3.y, acc1);
                acc0 = fmaf(w4, h4.x, acc0); acc1 = fmaf(w4, h4.y, acc1);
                acc0 = fmaf(w5, h5.x, acc0); acc1 = fmaf(w5, h5.y, acc1);
                acc0 = fmaf(w6, h6.x, acc0); acc1 = fmaf(w6, h6.y, acc1);
                acc0 = fmaf(w7, h7.x, acc0); acc1 = fmaf(w7, h7.y, acc1);
            } else {
                float h0 = loadS(H + (size_t)(e0 >> 15) * D + c0);
                float h1 = loadS(H + (size_t)(e1 >> 15) * D + c0);
                float h2 = loadS(H + (size_t)(e2 >> 15) * D + c0);
                float h3 = loadS(H + (size_t)(e3 >> 15) * D + c0);
                float h4 = loadS(H + (size_t)(e4 >> 15) * D + c0);
                float h5 = loadS(H + (size_t)(e5 >> 15) * D + c0);
                float h6 = loadS(H + (size_t)(e6 >> 15) * D + c0);
                float h7 = loadS(H + (size_t)(e7 >> 15) * D + c0);
                acc0 = fmaf(w0, h0, acc0);
                acc0 = fmaf(w1, h1, acc0);
                acc0 = fmaf(w2, h2, acc0);
                acc0 = fmaf(w3, h3, acc0);
                acc0 = fmaf(w4, h4, acc0);
                acc0 = fmaf(w5, h5, acc0);
                acc0 = fmaf(w6, h6, acc0);
                acc0 = fmaf(w7, h7, acc0);
            }
        }
    }

    if constexpr (VPT == 2) {
        if (BIAS) { acc0 += bias[c0]; acc1 += bias[c0 + 1]; }
        store2(Y + (size_t)i * D + c0, acc0, acc1);
    } else {
        if (BIAS) acc0 += bias[c0];
        storeS(Y + (size_t)i * D + c0, acc0);
    }
}

// ---------------------------------------------------------------------------
// GEMM dispatch wrapper; optional extra block zeroes next layer's BN stats.
// ---------------------------------------------------------------------------
template <int M, bool BN, typename TI, bool ZERO>
__global__ __launch_bounds__(256) void gemm_mfma_kernel(const TI* __restrict__ X,
                                                        const _Float16* __restrict__ WTg,
                                                        const float* __restrict__ sc,
                                                        const float* __restrict__ sh,
                                                        __half* __restrict__ Hout, int N,
                                                        float* __restrict__ gsum,
                                                        float* __restrict__ gsq, int GB) {
    __shared__ _Float16 WT[M * 136];
    if (ZERO && (int)blockIdx.x == GB) {
        if (threadIdx.x < 128) { gsum[threadIdx.x] = 0.0f; gsq[threadIdx.x] = 0.0f; }
        return;
    }
    gemm_body<M, BN, TI>(blockIdx.x, X, WTg, sc, sh, Hout, N, WT);
}

// ---------------------------------------------------------------------------
// BatchNorm statistics (fp16 Y)
// ---------------------------------------------------------------------------
__global__ void stats_kernel(const __half* __restrict__ Y, float* __restrict__ gsum,
                             float* __restrict__ gsq, int N) {
    __shared__ float ls[256], lq[256];
    const int tid = threadIdx.x;
    const int c = tid & 127;
    const int half_ = tid >> 7;
    float s = 0.0f, q = 0.0f;
    for (int row = blockIdx.x * 2 + half_; row < N; row += 512) {
        float v = __half2float(Y[(size_t)row * 128 + c]);
        s += v;
        q = fmaf(v, v, q);
    }
    ls[tid] = s; lq[tid] = q;
    __syncthreads();
    if (tid < 128) {
        atomicAdd(&gsum[c], ls[tid] + ls[tid + 128]);
        atomicAdd(&gsq[c],  lq[tid] + lq[tid + 128]);
    }
}

__global__ void finalize_stats_kernel(const float* __restrict__ gsum, const float* __restrict__ gsq,
                                      const float* __restrict__ gamma, const float* __restrict__ beta,
                                      float* __restrict__ sc, float* __restrict__ sh, int N) {
    int t = threadIdx.x;
    if (t < 128) {
        float inv_n = 1.0f / (float)N;
        float mean = gsum[t] * inv_n;
        float var = gsq[t] * inv_n - mean * mean;
        float scale = gamma[t] * rsqrtf(var + BN_EPS);
        sc[t] = scale;
        sh[t] = beta[t] - mean * scale;
    }
}

// ---------------------------------------------------------------------------
// Launch
// ---------------------------------------------------------------------------
extern "C" void kernel_launch(void* const* d_in, const int* in_sizes, int n_in,
                              void* d_out, int out_size, void* d_ws, size_t ws_size,
                              hipStream_t stream) {
    const float* x   = (const float*)d_in[0];
    const void*  ei  = d_in[1];
    const float* ew  = (const float*)d_in[2];
    const float* W1  = (const float*)d_in[3];
    const float* W2  = (const float*)d_in[5];
    const float* W3  = (const float*)d_in[7];
    const float* b3  = (const float*)d_in[8];
    const float* g1  = (const float*)d_in[9];
    const float* be1 = (const float*)d_in[10];
    const float* g2  = (const float*)d_in[11];
    const float* be2 = (const float*)d_in[12];
    float* out = (float*)d_out;

    const int N = in_sizes[0] / 128;   // 100000 (payload packing needs N <= 2^17)
    const int E = in_sizes[2];

    char* w = (char*)d_ws;
    size_t off = 0;
    auto alloc = [&](size_t bytes) -> void* {
        void* p = w + off;
        off += (bytes + 255) & ~(size_t)255;
        return p;
    };
    unsigned* pc     = (unsigned*)alloc(256 * 256 * 4);
    int*   tb        = (int*)  alloc(256 * 4);
    int*   bbase     = (int*)  alloc(256 * 4);
    unsigned long long* sortedE = (unsigned long long*)alloc((size_t)E * 8);
    float* dinv      = (float*)alloc((size_t)N * 4);
    int*   cnt       = (int*)  alloc((size_t)N * 4);
    int*   row_start = (int*)  alloc((size_t)N * 4);
    unsigned* edata  = (unsigned*)alloc((size_t)E * 4);
    int*   mode      = (int*)  alloc(256);
    float* gsum      = (float*)alloc(128 * 4);
    float* gsq       = (float*)alloc(128 * 4);
    float* scb       = (float*)alloc(128 * 4);
    float* shb       = (float*)alloc(128 * 4);
    _Float16* WT1    = (_Float16*)alloc(128 * 128 * 2);
    _Float16* WT2    = (_Float16*)alloc(128 * 128 * 2);
    _Float16* WT3    = (_Float16*)alloc(128 * 64 * 2);
    __half* H        = (__half*)alloc((size_t)N * 128 * 2);  // gemm out / agg in
    __half* Yh       = (__half*)alloc((size_t)N * 128 * 2);  // agg out / next gemm in
    (void)ws_size; (void)n_in; (void)out_size;

    const int epb   = (E + KB - 1) / KB;       // edges per chunk block
    const int nbuck = (N + (1 << BSH) - 1) >> BSH;  // coarse buckets (<=256)
    const int gb    = (N + 63) / 64;
    const int ab    = (N + 3) / 4;

    // 1: zero pc + detect dtype + W transposes
    init_kernel<<<64 + 1 + 160, 256, 0, stream>>>((const unsigned*)ei, 4096, mode, pc,
                                                  W1, W2, W3, WT1, WT2, WT3);
    // 2: coarse histogram (LDS atomics only)
    coarse_hist_kernel<<<KB, 256, 0, stream>>>(ei, mode, pc, E, epb);
    // 3: per-bucket scan over blocks; bucket bases (+ zero BN stats L1)
    scan_pc_kernel<<<nbuck, 256, 0, stream>>>(pc, tb);
    scan_buckets_kernel<<<1, 256, 0, stream>>>(tb, bbase, nbuck, gsum, gsq);
    // 4: GEMM1 fused with bucket scatter (no global atomics)
    sort_gemm1_kernel<<<gb + KB, 256, 0, stream>>>(ei, ew, pc, bbase, sortedE, mode, E,
                                                   epb, gb, x, WT1, H, N);
    // 5: per-bucket CSR build -> cnt, dinv, row_start, edata
    csr_build_kernel<<<nbuck, 256, 0, stream>>>(sortedE, bbase, tb, dinv, cnt, row_start,
                                                edata, N);

    // ---- L1: Yh = Ahat*H ----
    agg_kernel<128, false, __half><<<ab, 256, 0, stream>>>(H, edata, row_start, cnt, dinv, nullptr, Yh, N);
    stats_kernel<<<256, 256, 0, stream>>>(Yh, gsum, gsq, N);
    finalize_stats_kernel<<<1, 128, 0, stream>>>(gsum, gsq, g1, be1, scb, shb, N);

    // ---- L2: H = relu(bn(Yh))@W2 ; Yh = Ahat*H ----
    gemm_mfma_kernel<128, true, __half, true><<<gb + 1, 256, 0, stream>>>(Yh, WT2, scb, shb, H, N, gsum, gsq, gb);
    agg_kernel<128, false, __half><<<ab, 256, 0, stream>>>(H, edata, row_start, cnt, dinv, nullptr, Yh, N);
    stats_kernel<<<256, 256, 0, stream>>>(Yh, gsum, gsq, N);
    finalize_stats_kernel<<<1, 128, 0, stream>>>(gsum, gsq, g2, be2, scb, shb, N);

    // ---- L3: H64 = relu(bn(Yh))@W3 ; out = Ahat*H64 + b3 ----
    gemm_mfma_kernel<64, true, __half, false><<<gb, 256, 0, stream>>>(Yh, WT3, scb, shb, H, N, nullptr, nullptr, gb);
    agg_kernel<64, true, float><<<ab, 256, 0, stream>>>(H, edata, row_start, cnt, dinv, b3, out, N);
}